// Round 2
// baseline (3624.110 us; speedup 1.0000x reference)
//
#include <hip/hip_runtime.h>
#include <stdint.h>

// Problem constants
#define Bsz 16
#define Tlen 800
#define EPROJS 512
#define DUNITS 1024
#define ATT 512
#define ODIM 5000
#define LMAX 96
#define OL 97
#define NTOK (OL*Bsz)
#define G4 (4*DUNITS)
#define KX 1536             // [z0(1024) ; att_c(512)]
#define KA1 2048            // [z0(1024) ; z1(1024)]
#define SOS_ID (ODIM-1)
#define NWG 512
#define TCH 25              // t per S2 chunk (32 chunks * 25 = 800)

typedef unsigned short u16;
typedef unsigned int u32;
typedef unsigned long long u64;
typedef short bfrag8 __attribute__((ext_vector_type(8)));
typedef float f32x4 __attribute__((ext_vector_type(4)));

__device__ __forceinline__ float bf2f(u16 u){
  union { uint32_t u; float f; } v; v.u = ((uint32_t)u) << 16; return v.f;
}
__device__ __forceinline__ u16 f2bf(float f){
  union { float f; uint32_t u; } v; v.f = f;
  uint32_t r = v.u + 0x7FFFu + ((v.u >> 16) & 1u);
  return (u16)(r >> 16);
}
__device__ __forceinline__ float sigm(float x){ return 1.0f/(1.0f + __expf(-x)); }
__device__ __forceinline__ float tanh_f(float x){ return 1.0f - 2.0f/(__expf(2.0f*x) + 1.0f); }

// ---- LLC-coherent (agent-scope relaxed atomic) access
__device__ __forceinline__ u64 ald64(const void* p){
  return __hip_atomic_load((const u64*)p, __ATOMIC_RELAXED, __HIP_MEMORY_SCOPE_AGENT);
}
__device__ __forceinline__ void ast64(void* p, u64 v){
  __hip_atomic_store((u64*)p, v, __ATOMIC_RELAXED, __HIP_MEMORY_SCOPE_AGENT);
}
__device__ __forceinline__ float aldf(const float* p){
  return __hip_atomic_load(p, __ATOMIC_RELAXED, __HIP_MEMORY_SCOPE_AGENT);
}
__device__ __forceinline__ void astf(float* p, float v){
  __hip_atomic_store(p, v, __ATOMIC_RELAXED, __HIP_MEMORY_SCOPE_AGENT);
}
__device__ __forceinline__ void ast32(u32* p, u32 v){
  __hip_atomic_store(p, v, __ATOMIC_RELAXED, __HIP_MEMORY_SCOPE_AGENT);
}
__device__ __forceinline__ int ald32(const int* p){
  return __hip_atomic_load(p, __ATOMIC_RELAXED, __HIP_MEMORY_SCOPE_AGENT);
}
__device__ __forceinline__ bfrag8 aldfrag(const u16* p){
  union { u64 q[2]; bfrag8 f; } u;
  u.q[0] = ald64(p);
  u.q[1] = ald64(p + 4);
  return u.f;
}

// 16x16 tile MFMA loop, A-operand via LLC atomics, B-operand cached
__device__ __forceinline__ f32x4 mfma_loop_a(const u16* A, int lda,
                                             const u16* Bm, int ldb,
                                             int K, f32x4 acc){
  int lane = threadIdx.x & 63;
  const u16* pa = A + (size_t)(lane & 15) * lda + ((lane >> 4) * 8);
  const u16* pb = Bm + (size_t)(lane & 15) * ldb + ((lane >> 4) * 8);
  #pragma unroll 4
  for (int k = 0; k < K; k += 32){
    bfrag8 av = aldfrag(pa + k);
    bfrag8 bv = *(const bfrag8*)(pb + k);
    acc = __builtin_amdgcn_mfma_f32_16x16x32_bf16(av, bv, acc, 0, 0, 0);
  }
  return acc;
}
// fully-cached variant
__device__ __forceinline__ f32x4 mfma_loop(const u16* A, int lda,
                                           const u16* Bm, int ldb,
                                           int K, f32x4 acc){
  int lane = threadIdx.x & 63;
  const u16* pa = A + (size_t)(lane & 15) * lda + ((lane >> 4) * 8);
  const u16* pb = Bm + (size_t)(lane & 15) * ldb + ((lane >> 4) * 8);
  #pragma unroll 4
  for (int k = 0; k < K; k += 32){
    bfrag8 av = *(const bfrag8*)(pa + k);
    bfrag8 bv = *(const bfrag8*)(pb + k);
    acc = __builtin_amdgcn_mfma_f32_16x16x32_bf16(av, bv, acc, 0, 0, 0);
  }
  return acc;
}

// ---- monotone-counter dataflow sync ----
// Producers: data stores -> __syncthreads (vmcnt drained) -> fetch_add(+1).
// Consumers poll 1 (or 8 line-spread) counter words.
__device__ __forceinline__ void wait_cnt1(const int* p, int tgt){
  __syncthreads();
  if (threadIdx.x == 0){
    while (ald32(p) < tgt) __builtin_amdgcn_s_sleep(1);
  }
  __syncthreads();
}
__device__ __forceinline__ void wait_cnt8(const int* base, int tgt){
  __syncthreads();
  if (threadIdx.x < 64){
    int ln = threadIdx.x;
    bool d = (ln >= 8);
    for(;;){
      if (!d) d = (ald32(base + ln*32) >= tgt);
      if (__all(d)) break;
      __builtin_amdgcn_s_sleep(1);
    }
  }
  __syncthreads();
}
__device__ __forceinline__ void cnt_add(int* p){
  __syncthreads();   // drains this block's data stores (compiler emits vmcnt(0))
  if (threadIdx.x == 0)
    (void)__hip_atomic_fetch_add(p, 1, __ATOMIC_RELAXED, __HIP_MEMORY_SCOPE_AGENT);
}

// ---------------- setup kernels ----------------
__global__ __launch_bounds__(256) void k_zero(float* p, int n){
  int i = blockIdx.x*256 + threadIdx.x;
  if (i < n) p[i] = 0.f;
}
__global__ __launch_bounds__(256) void k_cvt(const float* src, u16* dst, int n){
  int i = blockIdx.x*256 + threadIdx.x, st = gridDim.x*256;
  for (; i < n; i += st) dst[i] = f2bf(src[i]);
}
// permuted-tile Wcat0: out[w][s][k]; row r=(s>>2)*1024+4w+(s&3); k<1024: Whh0, else Wih0 att cols
__global__ __launch_bounds__(256) void k_build_wc0p(const float* Whh0, const float* Wih0, u16* out){
  int i = blockIdx.x*256+threadIdx.x, n = 256*16*KX, st = gridDim.x*256;
  for (; i<n; i+=st){
    int k = i % KX, ws = i / KX;
    int s = ws & 15, w2 = ws >> 4;
    int r = (s>>2)*1024 + 4*w2 + (s&3);
    float v = (k < 1024) ? Whh0[(size_t)r*1024 + k] : Wih0[(size_t)r*KX + k];
    out[i] = f2bf(v);
  }
}
// permuted-tile Wcat1: k<1024: Wih1 (z0 half), else Whh1 (z1 half)
__global__ __launch_bounds__(256) void k_build_wc1p(const float* Wih1, const float* Whh1, u16* out){
  int i = blockIdx.x*256+threadIdx.x, n = 256*16*KA1, st = gridDim.x*256;
  for (; i<n; i+=st){
    int k = i % KA1, ws = i / KA1;
    int s = ws & 15, w2 = ws >> 4;
    int r = (s>>2)*1024 + 4*w2 + (s&3);
    float v = (k < 1024) ? Wih1[(size_t)r*1024 + k] : Whh1[(size_t)r*1024 + (k-1024)];
    out[i] = f2bf(v);
  }
}
// permuted-tile Wih0 embed-half: out[w][s][k] = Wih0[r(s,w)][k], k<1024
__global__ __launch_bounds__(256) void k_build_wih0p(const float* Wih0, u16* out){
  int i = blockIdx.x*256+threadIdx.x, n = 256*16*DUNITS, st = gridDim.x*256;
  for (; i<n; i+=st){
    int k = i % DUNITS, ws = i / DUNITS;
    int s = ws & 15, w2 = ws >> 4;
    int r = (s>>2)*1024 + 4*w2 + (s&3);
    out[i] = f2bf(Wih0[(size_t)r*KX + k]);
  }
}
__global__ __launch_bounds__(256) void k_build_aey(const float* embed, const int* ys_pad, u16* out){
  int i = blockIdx.x*256+threadIdx.x, n = NTOK*DUNITS, st = gridDim.x*256;
  for (; i<n; i+=st){
    int row = i / DUNITS, k = i % DUNITS;
    int l = row / Bsz, b = row % Bsz;
    int idx = (l == 0) ? SOS_ID : ys_pad[b*LMAX + (l-1)];
    out[i] = f2bf(embed[(size_t)idx*DUNITS + k]);
  }
}

__global__ __launch_bounds__(64) void k_gemm_preenc(const u16* hsb, const u16* Wenc,
                                                    const float* b_enc, u16* pre_enc){
  int bid = blockIdx.x;
  int m0 = (bid >> 5) * 16, n0 = (bid & 31) * 16;
  int lane = threadIdx.x & 63;
  int col = n0 + (lane & 15);
  float bias = b_enc[col];
  f32x4 acc = {bias, bias, bias, bias};
  acc = mfma_loop(hsb + (size_t)m0*EPROJS, EPROJS, Wenc + (size_t)n0*EPROJS, EPROJS, EPROJS, acc);
  int quad = lane >> 4;
  #pragma unroll
  for (int r = 0; r < 4; r++)
    pre_enc[(size_t)(m0 + quad*4 + r)*ATT + col] = f2bf(acc[r]);
}

__global__ __launch_bounds__(64) void k_gemm_logits(const u16* zall, const u16* Woutb,
                                                    const float* b_out, float* logits){
  const int NT = 313;
  int bid = blockIdx.x;
  int m0 = (bid / NT) * 16, n0 = (bid % NT) * 16;
  int lane = threadIdx.x & 63;
  int col = n0 + (lane & 15);
  bool ok = col < ODIM;
  int brow = ok ? col : 0;
  float bias = ok ? b_out[col] : 0.f;
  f32x4 acc = {bias, bias, bias, bias};
  const u16* pa = zall + (size_t)m0*DUNITS + (size_t)(lane & 15)*DUNITS + (lane >> 4)*8;
  const u16* pb = Woutb + (size_t)brow*DUNITS + (lane >> 4)*8;
  #pragma unroll 4
  for (int k = 0; k < DUNITS; k += 32){
    bfrag8 av = *(const bfrag8*)(pa + k);
    bfrag8 bv = *(const bfrag8*)(pb + k);
    acc = __builtin_amdgcn_mfma_f32_16x16x32_bf16(av, bv, acc, 0, 0, 0);
  }
  int quad = lane >> 4;
  if (ok){
    #pragma unroll
    for (int r = 0; r < 4; r++)
      logits[(size_t)(m0 + quad*4 + r)*ODIM + col] = acc[r];
  }
}

__global__ __launch_bounds__(256) void k_nll(const float* logits, const int* ys_pad, float* nll){
  int n = blockIdx.x;
  int b = n & 15, l = n >> 4;
  const float* row = logits + (size_t)n * ODIM;
  __shared__ float red[256];
  float m = -1e30f;
  for (int i = threadIdx.x; i < ODIM; i += 256) m = fmaxf(m, row[i]);
  red[threadIdx.x] = m; __syncthreads();
  for (int s = 128; s > 0; s >>= 1){
    if (threadIdx.x < s) red[threadIdx.x] = fmaxf(red[threadIdx.x], red[threadIdx.x + s]);
    __syncthreads();
  }
  float M = red[0]; __syncthreads();
  float sum = 0.f;
  for (int i = threadIdx.x; i < ODIM; i += 256) sum += __expf(row[i] - M);
  red[threadIdx.x] = sum; __syncthreads();
  for (int s = 128; s > 0; s >>= 1){
    if (threadIdx.x < s) red[threadIdx.x] += red[threadIdx.x + s];
    __syncthreads();
  }
  if (threadIdx.x == 0){
    int tgt = (l < LMAX) ? ys_pad[b*LMAX + l] : (ODIM - 1);
    nll[n] = (M + __logf(red[0])) - row[tgt];
  }
}

__global__ __launch_bounds__(256) void k_loss(const float* nll, float* out){
  __shared__ float red[256];
  float s = 0.f;
  for (int i = threadIdx.x; i < NTOK; i += 256) s += nll[i];
  red[threadIdx.x] = s; __syncthreads();
  for (int st = 128; st > 0; st >>= 1){
    if (threadIdx.x < st) red[threadIdx.x] += red[threadIdx.x + st];
    __syncthreads();
  }
  if (threadIdx.x == 0) out[0] = red[0] * ((float)LMAX / (float)NTOK);
}

// ---------------- persistent recurrence kernel ----------------
// Chain per step (3 hops): cntz0 -> dp -> cntdp -> S2(+elected attc reduce)
//   -> cntatt -> S4 -> cntz0. gates1 runs off-path after S2.
// Counter layout in bar (ints, 32-int = 128B line spacing):
//   cntz0[8] @0(stride32), cntdp @256, cntatt @288, cntz1[8] @320(stride32),
//   partcnt[16] @576(stride32)
__global__ __launch_bounds__(256, 2) void k_persist(
  const u16* __restrict__ peb, const u16* __restrict__ hsb,
  const u16* __restrict__ wc0p, const u16* __restrict__ wc1p, const u16* __restrict__ wdecb,
  const u16* __restrict__ wih0p, const u16* __restrict__ aey,
  const float* __restrict__ b_ih0, const float* __restrict__ b_hh0,
  const float* __restrict__ b_ih1, const float* __restrict__ b_hh1,
  const float* __restrict__ gvec, const int* __restrict__ hlens,
  u16* a1b0, u16* a1b1, float* dpbuf, float* part, float* partS, u16* xatt,
  u16* zall, int* bar)
{
  __shared__ __align__(16) u16 s_pe[TCH*512];
  __shared__ __align__(16) u16 s_hs[TCH*512];
  __shared__ __align__(16) float s_dp[512];
  __shared__ __align__(16) float s_gv[512];
  __shared__ __align__(16) float s_red[2048];
  __shared__ float s_c[64];
  __shared__ float s_bias[16];
  __shared__ float s_bias0[16];
  __shared__ float s_sp[4];
  __shared__ __align__(8) u16 s_h[64];
  __shared__ int s_elect;

  int tid = threadIdx.x, blk = blockIdx.x;
  int wv = tid >> 6, ln = tid & 63;
  int s2_b = blk >> 5, s2_ch = blk & 31;
  int t0 = s2_ch * TCH;
  int hl = hlens[s2_b];
  bool isLow = (blk < 256);
  int hw = blk - 256;
  bool isdp = (!isLow) && ((hw & 7) == 0);   // dp duty spread across XCDs
  int wdp = hw >> 3;

  int* cntz0  = bar;            // 8 words, stride 32
  int* cntdp  = bar + 256;
  int* cntatt = bar + 288;
  int* cntz1  = bar + 320;      // 8 words, stride 32
  int* partcnt= bar + 576;      // 16 words, stride 32

  // ---- init: stage LDS-persistent data ----
  {
    const bfrag8* src_pe = (const bfrag8*)(peb + ((size_t)(s2_b*Tlen + t0))*512);
    const bfrag8* src_hs = (const bfrag8*)(hsb + ((size_t)(s2_b*Tlen + t0))*512);
    for (int idx = tid; idx < TCH*512/8; idx += 256){
      ((bfrag8*)s_pe)[idx] = src_pe[idx];
      ((bfrag8*)s_hs)[idx] = src_hs[idx];
    }
    for (int a = tid; a < 512; a += 256) s_gv[a] = gvec[a];
    if (isLow && tid < 16){
      int r = (tid>>2)*1024 + 4*blk + (tid&3);
      s_bias[tid] = b_ih1[r] + b_hh1[r];
    }
    if (!isLow && tid < 16){
      int r = (tid>>2)*1024 + 4*hw + (tid&3);
      s_bias0[tid] = b_ih0[r] + b_hh0[r];
    }
    if (tid < 64) s_c[tid] = 0.f;
  }
  __syncthreads();

  for (int i = 0; i < OL; i++){
    int par = i & 1;
    const u16* a1r = par ? a1b1 : a1b0;
    u16* a1w = par ? a1b0 : a1b1;
    float* dpc   = dpbuf + (size_t)par*(16*512);
    float* partc = part  + (size_t)par*(16*32*512);
    float* pSc   = partS + (size_t)par*(16*32);
    u16*   xac   = xatt  + (size_t)par*(16*512);

    f32x4 acc0 = {0.f,0.f,0.f,0.f};

    if (!isLow){
      // ======== dp stage (critical): only dp-duty blocks ========
      if (isdp){
        if (i >= 1) wait_cnt8(cntz0, i*32);
        const u16* btd = wdecb + (size_t)wdp*16*DUNITS;
        f32x4 ad = {0.f,0.f,0.f,0.f};
        ad = mfma_loop_a(a1r + wv*256, KA1, btd + wv*256, DUNITS, 256, ad);
        int q = ln >> 4;
        #pragma unroll
        for (int r = 0; r < 4; r++) s_red[wv*256 + (q*4+r)*16 + (ln & 15)] = ad[r];
        __syncthreads();
        {
          float val = s_red[tid] + s_red[256+tid] + s_red[512+tid] + s_red[768+tid];
          int b = tid >> 4, al = tid & 15;
          astf(&dpc[b*512 + wdp*16 + al], val);
        }
        cnt_add(cntdp);
      }
      // pregate tile for step i (pure cached loads, hides under dp wait)
      acc0 = mfma_loop(aey + ((size_t)i*Bsz)*DUNITS + wv*256, DUNITS,
                       wih0p + (size_t)hw*16*DUNITS + wv*256, DUNITS, 256, acc0);
    }

    // ======== S2: energies + attc partials (all 512 blocks) ========
    wait_cnt1(cntdp, (i + 1)*32);
    ((u64*)s_dp)[tid] = ald64(((const u64*)(dpc + s2_b*512)) + tid);
    __syncthreads();
    {
      float dpr[8], gvr[8];
      {
        float4 d1 = *(const float4*)&s_dp[ln*8];
        float4 d2 = *(const float4*)&s_dp[ln*8+4];
        float4 g1 = *(const float4*)&s_gv[ln*8];
        float4 g2 = *(const float4*)&s_gv[ln*8+4];
        dpr[0]=d1.x; dpr[1]=d1.y; dpr[2]=d1.z; dpr[3]=d1.w;
        dpr[4]=d2.x; dpr[5]=d2.y; dpr[6]=d2.z; dpr[7]=d2.w;
        gvr[0]=g1.x; gvr[1]=g1.y; gvr[2]=g1.z; gvr[3]=g1.w;
        gvr[4]=g2.x; gvr[5]=g2.y; gvr[6]=g2.z; gvr[7]=g2.w;
      }
      float attc[8];
      #pragma unroll
      for (int j = 0; j < 8; j++) attc[j] = 0.f;
      float sp = 0.f;
      for (int lt = wv; lt < TCH; lt += 4){
        int t = t0 + lt;
        bool valid = (t < hl);
        float e = 0.f;
        if (valid){
          bfrag8 pv = *(const bfrag8*)&s_pe[lt*512 + ln*8];
          #pragma unroll
          for (int j = 0; j < 8; j++){
            float x = bf2f(((u16*)&pv)[j]) + dpr[j];
            e += gvr[j] * tanh_f(x);
          }
        }
        #pragma unroll
        for (int off = 32; off > 0; off >>= 1) e += __shfl_xor(e, off, 64);
        float p = valid ? __expf(2.0f * e) : 0.f;
        if (ln == 0) sp += p;
        bfrag8 hv = *(const bfrag8*)&s_hs[lt*512 + ln*8];
        #pragma unroll
        for (int j = 0; j < 8; j++) attc[j] += p * bf2f(((u16*)&hv)[j]);
      }
      *(float4*)&s_red[wv*512 + ln*8]     = make_float4(attc[0],attc[1],attc[2],attc[3]);
      *(float4*)&s_red[wv*512 + ln*8 + 4] = make_float4(attc[4],attc[5],attc[6],attc[7]);
      if (ln == 0) s_sp[wv] = sp;
      __syncthreads();
      {
        int e0 = 2*tid;
        float v0 = s_red[e0]   + s_red[512+e0]   + s_red[1024+e0]   + s_red[1536+e0];
        float v1 = s_red[e0+1] + s_red[512+e0+1] + s_red[1024+e0+1] + s_red[1536+e0+1];
        union { float f[2]; u64 q; } pu; pu.f[0]=v0; pu.f[1]=v1;
        ast64(&partc[((size_t)(s2_b*32 + s2_ch))*512 + e0], pu.q);
      }
      if (tid == 0) astf(&pSc[s2_b*32 + s2_ch], s_sp[0]+s_sp[1]+s_sp[2]+s_sp[3]);
    }
    // ---- election: last-arriving chunk block of batch b does the reduce ----
    __syncthreads();   // drain partc/pSc stores
    if (tid == 0){
      int old = __hip_atomic_fetch_add(&partcnt[s2_b], 1,
                                       __ATOMIC_RELAXED, __HIP_MEMORY_SCOPE_AGENT);
      s_elect = (old == i*32 + 31);
    }
    __syncthreads();
    if (s_elect){
      // attc reduce: each thread owns element pair (2*tid, 2*tid+1), c2 ascending
      float v0 = 0.f, v1 = 0.f;
      const u64* pp = (const u64*)(partc + ((size_t)s2_b*32)*512) + tid;
      #pragma unroll 8
      for (int c2 = 0; c2 < 32; c2++){
        union { u64 q; float f[2]; } x; x.q = ald64(pp + (size_t)c2*256);
        v0 += x.f[0]; v1 += x.f[1];
      }
      if (wv == 0){
        float sp = (ln < 32) ? aldf(&pSc[s2_b*32 + ln]) : 0.f;
        #pragma unroll
        for (int off = 32; off > 0; off >>= 1) sp += __shfl_xor(sp, off, 64);
        if (ln == 0) s_sp[0] = 1.0f / sp;
      }
      __syncthreads();
      float rinv = s_sp[0];
      u32 wpk = (u32)f2bf(v0*rinv) | ((u32)f2bf(v1*rinv) << 16);
      ast32(((u32*)xac) + s2_b*256 + tid, wpk);
      __syncthreads();   // drain xatt stores
      if (tid == 0)
        (void)__hip_atomic_fetch_add(cntatt, 1, __ATOMIC_RELAXED, __HIP_MEMORY_SCOPE_AGENT);
    }

    if (isLow){
      // ======== gates1 + cell1 (off critical path; overlaps S4/dp) ========
      if (i >= 1){
        if (i >= 2) wait_cnt8(cntz1, (i-1)*32);
        const u16* bt = wc1p + (size_t)blk*16*KA1;
        f32x4 acc = {0.f,0.f,0.f,0.f};
        acc = mfma_loop_a(a1r + wv*512, KA1, bt + wv*512, KA1, 512, acc);
        int q = ln >> 4;
        #pragma unroll
        for (int r = 0; r < 4; r++) s_red[wv*256 + (q*4+r)*16 + (ln & 15)] = acc[r];
        __syncthreads();
        {
          float val = s_red[tid] + s_red[256+tid] + s_red[512+tid] + s_red[768+tid]
                    + s_bias[tid & 15];
          s_red[1024 + tid] = val;
        }
        __syncthreads();
        if (tid < 64){
          int b = tid >> 2, jj = tid & 3;
          float gi = s_red[1024 + b*16 + jj];
          float gf = s_red[1024 + b*16 + 4 + jj];
          float gg = s_red[1024 + b*16 + 8 + jj];
          float go = s_red[1024 + b*16 + 12 + jj];
          float c = s_c[tid];
          float cn = sigm(gf)*c + sigm(gi)*tanh_f(gg);
          float h  = sigm(go)*tanh_f(cn);
          s_c[tid] = cn;
          s_h[tid] = f2bf(h);
        }
        __syncthreads();
        if (tid < 16){
          u64 hq = ((u64*)s_h)[tid];
          ast64(&a1w[tid*KA1 + 1024 + 4*blk], hq);
          *(u64*)&zall[((size_t)(i-1)*Bsz + tid)*DUNITS + 4*blk] = hq;
        }
        cnt_add(cntz1 + (blk & 7)*32);
      }
    } else {
      // ======== acc0 z0-part (overlaps elected reduce), then S4 ========
      const u16* bt0 = wc0p + (size_t)hw*16*KX;
      acc0 = mfma_loop_a(a1r + wv*256, KA1, bt0 + wv*256, KX, 256, acc0);
      wait_cnt1(cntatt, (i + 1)*16);
      acc0 = mfma_loop_a(xac + wv*128, 512, bt0 + 1024 + wv*128, KX, 128, acc0);
      int q = ln >> 4;
      #pragma unroll
      for (int r = 0; r < 4; r++) s_red[wv*256 + (q*4+r)*16 + (ln & 15)] = acc0[r];
      __syncthreads();
      {
        float val = s_red[tid] + s_red[256+tid] + s_red[512+tid] + s_red[768+tid]
                  + s_bias0[tid & 15];
        s_red[1024 + tid] = val;
      }
      __syncthreads();
      if (tid < 64){
        int b = tid >> 2, jj = tid & 3;
        float gi = s_red[1024 + b*16 + jj];
        float gf = s_red[1024 + b*16 + 4 + jj];
        float gg = s_red[1024 + b*16 + 8 + jj];
        float go = s_red[1024 + b*16 + 12 + jj];
        float c = s_c[tid];
        float cn = sigm(gf)*c + sigm(gi)*tanh_f(gg);
        float h  = sigm(go)*tanh_f(cn);
        s_c[tid] = cn;
        s_h[tid] = f2bf(h);
      }
      __syncthreads();
      if (tid < 16) ast64(&a1w[tid*KA1 + 4*hw], ((u64*)s_h)[tid]);
      cnt_add(cntz0 + (hw & 7)*32);
    }
  }

  // ======== tail: gates1 + cell1 for step 96 ========
  if (isLow){
    wait_cnt8(cntz0, OL*32);
    wait_cnt8(cntz1, (OL-1)*32);
    const u16* a1r = (OL & 1) ? a1b1 : a1b0;
    const u16* bt = wc1p + (size_t)blk*16*KA1;
    f32x4 acc = {0.f,0.f,0.f,0.f};
    acc = mfma_loop_a(a1r + wv*512, KA1, bt + wv*512, KA1, 512, acc);
    int q = ln >> 4;
    #pragma unroll
    for (int r = 0; r < 4; r++) s_red[wv*256 + (q*4+r)*16 + (ln & 15)] = acc[r];
    __syncthreads();
    {
      float val = s_red[tid] + s_red[256+tid] + s_red[512+tid] + s_red[768+tid]
                + s_bias[tid & 15];
      s_red[1024 + tid] = val;
    }
    __syncthreads();
    if (tid < 64){
      int b = tid >> 2, jj = tid & 3;
      float gi = s_red[1024 + b*16 + jj];
      float gf = s_red[1024 + b*16 + 4 + jj];
      float gg = s_red[1024 + b*16 + 8 + jj];
      float go = s_red[1024 + b*16 + 12 + jj];
      float c = s_c[tid];
      float cn = sigm(gf)*c + sigm(gi)*tanh_f(gg);
      float h  = sigm(go)*tanh_f(cn);
      s_h[tid] = f2bf(h);
    }
    __syncthreads();
    if (tid < 16)
      *(u64*)&zall[((size_t)LMAX*Bsz + tid)*DUNITS + 4*blk] = ((u64*)s_h)[tid];
  }
}

extern "C" void kernel_launch(void* const* d_in, const int* in_sizes, int n_in,
                              void* d_out, int out_size, void* d_ws, size_t ws_size,
                              hipStream_t stream)
{
  const float* hs     = (const float*)d_in[0];
  const int*   hlens  = (const int*)d_in[1];
  const int*   ys_pad = (const int*)d_in[2];
  const float* embed  = (const float*)d_in[3];
  const float* W_ih0  = (const float*)d_in[4];
  const float* W_hh0  = (const float*)d_in[5];
  const float* b_ih0  = (const float*)d_in[6];
  const float* b_hh0  = (const float*)d_in[7];
  const float* W_ih1  = (const float*)d_in[8];
  const float* W_hh1  = (const float*)d_in[9];
  const float* b_ih1  = (const float*)d_in[10];
  const float* b_hh1  = (const float*)d_in[11];
  const float* W_enc  = (const float*)d_in[12];
  const float* b_enc  = (const float*)d_in[13];
  const float* W_dec  = (const float*)d_in[14];
  const float* gvec   = (const float*)d_in[15];
  const float* W_out  = (const float*)d_in[16];
  const float* b_out  = (const float*)d_in[17];
  (void)in_sizes; (void)n_in; (void)out_size; (void)ws_size;

  char* w = (char*)d_ws;
  size_t off = 0;
  auto alloc = [&](size_t bytes)->char*{
    char* ptr = w + off;
    off += (bytes + 255) & ~(size_t)255;
    return ptr;
  };
  // --- zeroed state block: counters + a1 double buffers ---
  int*   bar  = (int*)alloc(8192);
  u16*  a1b0  = (u16*)alloc(Bsz*KA1*2);
  u16*  a1b1  = (u16*)alloc(Bsz*KA1*2);
  size_t state_bytes = off;
  // --- scratch (written before read every step) ---
  float* dpbuf = (float*)alloc(2*(size_t)Bsz*ATT*4);
  float* part  = (float*)alloc(2*(size_t)Bsz*32*512*4);
  float* partS = (float*)alloc(2*(size_t)Bsz*32*4);
  u16*  xatt   = (u16*)alloc(2*(size_t)Bsz*512*2);
  u16*  hsb    = (u16*)alloc((size_t)Bsz*Tlen*EPROJS*2);
  u16*  peb    = (u16*)alloc((size_t)Bsz*Tlen*ATT*2);
  u16*  wencb  = (u16*)alloc((size_t)ATT*EPROJS*2);
  u16*  wdecb  = (u16*)alloc((size_t)ATT*DUNITS*2);
  u16*  wc0p   = (u16*)alloc((size_t)G4*KX*2);
  u16*  wc1p   = (u16*)alloc((size_t)G4*KA1*2);
  u16*  wih0p  = (u16*)alloc((size_t)G4*DUNITS*2);
  u16*  woutb  = (u16*)alloc((size_t)ODIM*DUNITS*2);
  u16*  aey    = (u16*)alloc((size_t)NTOK*DUNITS*2);
  u16*  zall   = (u16*)alloc((size_t)NTOK*DUNITS*2);
  float* logits= (float*)alloc((size_t)NTOK*ODIM*4);
  float* nll   = (float*)alloc(NTOK*4);

  {
    int n = (int)(state_bytes / 4);
    k_zero<<<(n + 255)/256, 256, 0, stream>>>((float*)w, n);
  }

  k_cvt<<<2048,256,0,stream>>>(hs, hsb, Bsz*Tlen*EPROJS);
  k_cvt<<<256,256,0,stream>>>(W_enc, wencb, ATT*EPROJS);
  k_cvt<<<512,256,0,stream>>>(W_dec, wdecb, ATT*DUNITS);
  k_cvt<<<2048,256,0,stream>>>(W_out, woutb, ODIM*DUNITS);
  k_build_wc0p<<<4096,256,0,stream>>>(W_hh0, W_ih0, wc0p);
  k_build_wc1p<<<4096,256,0,stream>>>(W_ih1, W_hh1, wc1p);
  k_build_wih0p<<<4096,256,0,stream>>>(W_ih0, wih0p);
  k_build_aey<<<1024,256,0,stream>>>(embed, ys_pad, aey);

  k_gemm_preenc<<<(Bsz*Tlen/16)*(ATT/16), 64, 0, stream>>>(hsb, wencb, b_enc, peb);

  // persistent cooperative recurrence
  {
    void* args[] = {
      (void*)&peb, (void*)&hsb, (void*)&wc0p, (void*)&wc1p, (void*)&wdecb,
      (void*)&wih0p, (void*)&aey, (void*)&b_ih0, (void*)&b_hh0,
      (void*)&b_ih1, (void*)&b_hh1, (void*)&gvec, (void*)&hlens,
      (void*)&a1b0, (void*)&a1b1, (void*)&dpbuf, (void*)&part, (void*)&partS,
      (void*)&xatt, (void*)&zall, (void*)&bar
    };
    hipLaunchCooperativeKernel((const void*)k_persist, dim3(NWG), dim3(256),
                               args, 0, stream);
  }

  k_gemm_logits<<<OL*313, 64, 0, stream>>>(zall, woutb, b_out, logits);
  k_nll<<<NTOK,256,0,stream>>>(logits, ys_pad, nll);
  k_loss<<<1,256,0,stream>>>(nll, (float*)d_out);
}

// Round 3
// 3287.519 us; speedup vs baseline: 1.1024x; 1.1024x over previous
//
#include <hip/hip_runtime.h>
#include <stdint.h>

// Problem constants
#define Bsz 16
#define Tlen 800
#define EPROJS 512
#define DUNITS 1024
#define ATT 512
#define ODIM 5000
#define LMAX 96
#define OL 97
#define NTOK (OL*Bsz)
#define G4 (4*DUNITS)
#define KX 1536             // [z0(1024) ; att_c(512)]
#define KA1 2048            // [z0(1024) ; z1(1024)]
#define SOS_ID (ODIM-1)
#define NWG 512
#define TCH 25              // t per S2 chunk (32 chunks * 25 = 800)

typedef unsigned short u16;
typedef unsigned int u32;
typedef unsigned long long u64;
typedef short bfrag8 __attribute__((ext_vector_type(8)));
typedef float f32x4 __attribute__((ext_vector_type(4)));

__device__ __forceinline__ float bf2f(u16 u){
  union { uint32_t u; float f; } v; v.u = ((uint32_t)u) << 16; return v.f;
}
__device__ __forceinline__ u16 f2bf(float f){
  union { float f; uint32_t u; } v; v.f = f;
  uint32_t r = v.u + 0x7FFFu + ((v.u >> 16) & 1u);
  return (u16)(r >> 16);
}
__device__ __forceinline__ float sigm(float x){ return 1.0f/(1.0f + __expf(-x)); }
__device__ __forceinline__ float tanh_f(float x){ return 1.0f - 2.0f/(__expf(2.0f*x) + 1.0f); }

// ---- LLC-coherent (agent-scope relaxed atomic) access
__device__ __forceinline__ u64 ald64(const void* p){
  return __hip_atomic_load((const u64*)p, __ATOMIC_RELAXED, __HIP_MEMORY_SCOPE_AGENT);
}
__device__ __forceinline__ void ast64(void* p, u64 v){
  __hip_atomic_store((u64*)p, v, __ATOMIC_RELAXED, __HIP_MEMORY_SCOPE_AGENT);
}
__device__ __forceinline__ float aldf(const float* p){
  return __hip_atomic_load(p, __ATOMIC_RELAXED, __HIP_MEMORY_SCOPE_AGENT);
}
__device__ __forceinline__ void astf(float* p, float v){
  __hip_atomic_store(p, v, __ATOMIC_RELAXED, __HIP_MEMORY_SCOPE_AGENT);
}
__device__ __forceinline__ void ast32(u32* p, u32 v){
  __hip_atomic_store(p, v, __ATOMIC_RELAXED, __HIP_MEMORY_SCOPE_AGENT);
}
__device__ __forceinline__ int ald32(const int* p){
  return __hip_atomic_load(p, __ATOMIC_RELAXED, __HIP_MEMORY_SCOPE_AGENT);
}
__device__ __forceinline__ bfrag8 aldfrag(const u16* p){
  union { u64 q[2]; bfrag8 f; } u;
  u.q[0] = ald64(p);
  u.q[1] = ald64(p + 4);
  return u.f;
}

// 16x16 tile MFMA loop, A-operand via LLC atomics, B-operand cached
__device__ __forceinline__ f32x4 mfma_loop_a(const u16* A, int lda,
                                             const u16* Bm, int ldb,
                                             int K, f32x4 acc){
  int lane = threadIdx.x & 63;
  const u16* pa = A + (size_t)(lane & 15) * lda + ((lane >> 4) * 8);
  const u16* pb = Bm + (size_t)(lane & 15) * ldb + ((lane >> 4) * 8);
  #pragma unroll 4
  for (int k = 0; k < K; k += 32){
    bfrag8 av = aldfrag(pa + k);
    bfrag8 bv = *(const bfrag8*)(pb + k);
    acc = __builtin_amdgcn_mfma_f32_16x16x32_bf16(av, bv, acc, 0, 0, 0);
  }
  return acc;
}
// fully-cached variant
__device__ __forceinline__ f32x4 mfma_loop(const u16* A, int lda,
                                           const u16* Bm, int ldb,
                                           int K, f32x4 acc){
  int lane = threadIdx.x & 63;
  const u16* pa = A + (size_t)(lane & 15) * lda + ((lane >> 4) * 8);
  const u16* pb = Bm + (size_t)(lane & 15) * ldb + ((lane >> 4) * 8);
  #pragma unroll 4
  for (int k = 0; k < K; k += 32){
    bfrag8 av = *(const bfrag8*)(pa + k);
    bfrag8 bv = *(const bfrag8*)(pb + k);
    acc = __builtin_amdgcn_mfma_f32_16x16x32_bf16(av, bv, acc, 0, 0, 0);
  }
  return acc;
}

// ---- store-slot dataflow sync ----
// wave 0 polls n64 u64 words (= 2*n64 int epochs), all >= tgt.
// Epochs are monotone: once a word is satisfied, stop reloading it (dedup).
__device__ __forceinline__ void wait_slots(const u64* s64, int n64, int tgt){
  __syncthreads();
  if (threadIdx.x < 64){
    int ln = threadIdx.x;
    bool d0 = (ln >= n64), d1 = (ln + 64 >= n64);
    for(;;){
      if (!d0){ u64 v = ald64(&s64[ln]);
        d0 = ((int)(u32)v >= tgt) && ((int)(u32)(v >> 32) >= tgt); }
      if (!d1){ u64 v = ald64(&s64[ln + 64]);
        d1 = ((int)(u32)v >= tgt) && ((int)(u32)(v >> 32) >= tgt); }
      if (__all(d0 && d1)) break;
      __builtin_amdgcn_s_sleep(1);
    }
  }
  __syncthreads();
}
// producer: data stores -> __syncthreads (vmcnt drained) -> own-slot store
__device__ __forceinline__ void signal_slot(int* slot, int val){
  __syncthreads();
  if (threadIdx.x == 0) ast32((u32*)slot, (u32)val);
}

// ---------------- setup kernels ----------------
__global__ __launch_bounds__(256) void k_zero(float* p, int n){
  int i = blockIdx.x*256 + threadIdx.x;
  if (i < n) p[i] = 0.f;
}
__global__ __launch_bounds__(256) void k_cvt(const float* src, u16* dst, int n){
  int i = blockIdx.x*256 + threadIdx.x, st = gridDim.x*256;
  for (; i < n; i += st) dst[i] = f2bf(src[i]);
}
// permuted-tile Wcat0: out[w][s][k]; row r=(s>>2)*1024+4w+(s&3); k<1024: Whh0, else Wih0 att cols
__global__ __launch_bounds__(256) void k_build_wc0p(const float* Whh0, const float* Wih0, u16* out){
  int i = blockIdx.x*256+threadIdx.x, n = 256*16*KX, st = gridDim.x*256;
  for (; i<n; i+=st){
    int k = i % KX, ws = i / KX;
    int s = ws & 15, w2 = ws >> 4;
    int r = (s>>2)*1024 + 4*w2 + (s&3);
    float v = (k < 1024) ? Whh0[(size_t)r*1024 + k] : Wih0[(size_t)r*KX + k];
    out[i] = f2bf(v);
  }
}
// permuted-tile Wcat1: k<1024: Wih1 (z0 half), else Whh1 (z1 half)
__global__ __launch_bounds__(256) void k_build_wc1p(const float* Wih1, const float* Whh1, u16* out){
  int i = blockIdx.x*256+threadIdx.x, n = 256*16*KA1, st = gridDim.x*256;
  for (; i<n; i+=st){
    int k = i % KA1, ws = i / KA1;
    int s = ws & 15, w2 = ws >> 4;
    int r = (s>>2)*1024 + 4*w2 + (s&3);
    float v = (k < 1024) ? Wih1[(size_t)r*1024 + k] : Whh1[(size_t)r*1024 + (k-1024)];
    out[i] = f2bf(v);
  }
}
// permuted-tile Wih0 embed-half: out[w][s][k] = Wih0[r(s,w)][k], k<1024
__global__ __launch_bounds__(256) void k_build_wih0p(const float* Wih0, u16* out){
  int i = blockIdx.x*256+threadIdx.x, n = 256*16*DUNITS, st = gridDim.x*256;
  for (; i<n; i+=st){
    int k = i % DUNITS, ws = i / DUNITS;
    int s = ws & 15, w2 = ws >> 4;
    int r = (s>>2)*1024 + 4*w2 + (s&3);
    out[i] = f2bf(Wih0[(size_t)r*KX + k]);
  }
}
__global__ __launch_bounds__(256) void k_build_aey(const float* embed, const int* ys_pad, u16* out){
  int i = blockIdx.x*256+threadIdx.x, n = NTOK*DUNITS, st = gridDim.x*256;
  for (; i<n; i+=st){
    int row = i / DUNITS, k = i % DUNITS;
    int l = row / Bsz, b = row % Bsz;
    int idx = (l == 0) ? SOS_ID : ys_pad[b*LMAX + (l-1)];
    out[i] = f2bf(embed[(size_t)idx*DUNITS + k]);
  }
}

__global__ __launch_bounds__(64) void k_gemm_preenc(const u16* hsb, const u16* Wenc,
                                                    const float* b_enc, u16* pre_enc){
  int bid = blockIdx.x;
  int m0 = (bid >> 5) * 16, n0 = (bid & 31) * 16;
  int lane = threadIdx.x & 63;
  int col = n0 + (lane & 15);
  float bias = b_enc[col];
  f32x4 acc = {bias, bias, bias, bias};
  acc = mfma_loop(hsb + (size_t)m0*EPROJS, EPROJS, Wenc + (size_t)n0*EPROJS, EPROJS, EPROJS, acc);
  int quad = lane >> 4;
  #pragma unroll
  for (int r = 0; r < 4; r++)
    pre_enc[(size_t)(m0 + quad*4 + r)*ATT + col] = f2bf(acc[r]);
}

__global__ __launch_bounds__(64) void k_gemm_logits(const u16* zall, const u16* Woutb,
                                                    const float* b_out, float* logits){
  const int NT = 313;
  int bid = blockIdx.x;
  int m0 = (bid / NT) * 16, n0 = (bid % NT) * 16;
  int lane = threadIdx.x & 63;
  int col = n0 + (lane & 15);
  bool ok = col < ODIM;
  int brow = ok ? col : 0;
  float bias = ok ? b_out[col] : 0.f;
  f32x4 acc = {bias, bias, bias, bias};
  const u16* pa = zall + (size_t)m0*DUNITS + (size_t)(lane & 15)*DUNITS + (lane >> 4)*8;
  const u16* pb = Woutb + (size_t)brow*DUNITS + (lane >> 4)*8;
  #pragma unroll 4
  for (int k = 0; k < DUNITS; k += 32){
    bfrag8 av = *(const bfrag8*)(pa + k);
    bfrag8 bv = *(const bfrag8*)(pb + k);
    acc = __builtin_amdgcn_mfma_f32_16x16x32_bf16(av, bv, acc, 0, 0, 0);
  }
  int quad = lane >> 4;
  if (ok){
    #pragma unroll
    for (int r = 0; r < 4; r++)
      logits[(size_t)(m0 + quad*4 + r)*ODIM + col] = acc[r];
  }
}

__global__ __launch_bounds__(256) void k_nll(const float* logits, const int* ys_pad, float* nll){
  int n = blockIdx.x;
  int b = n & 15, l = n >> 4;
  const float* row = logits + (size_t)n * ODIM;
  __shared__ float red[256];
  float m = -1e30f;
  for (int i = threadIdx.x; i < ODIM; i += 256) m = fmaxf(m, row[i]);
  red[threadIdx.x] = m; __syncthreads();
  for (int s = 128; s > 0; s >>= 1){
    if (threadIdx.x < s) red[threadIdx.x] = fmaxf(red[threadIdx.x], red[threadIdx.x + s]);
    __syncthreads();
  }
  float M = red[0]; __syncthreads();
  float sum = 0.f;
  for (int i = threadIdx.x; i < ODIM; i += 256) sum += __expf(row[i] - M);
  red[threadIdx.x] = sum; __syncthreads();
  for (int s = 128; s > 0; s >>= 1){
    if (threadIdx.x < s) red[threadIdx.x] += red[threadIdx.x + s];
    __syncthreads();
  }
  if (threadIdx.x == 0){
    int tgt = (l < LMAX) ? ys_pad[b*LMAX + l] : (ODIM - 1);
    nll[n] = (M + __logf(red[0])) - row[tgt];
  }
}

__global__ __launch_bounds__(256) void k_loss(const float* nll, float* out){
  __shared__ float red[256];
  float s = 0.f;
  for (int i = threadIdx.x; i < NTOK; i += 256) s += nll[i];
  red[threadIdx.x] = s; __syncthreads();
  for (int st = 128; st > 0; st >>= 1){
    if (threadIdx.x < st) red[threadIdx.x] += red[threadIdx.x + st];
    __syncthreads();
  }
  if (threadIdx.x == 0) out[0] = red[0] * ((float)LMAX / (float)NTOK);
}

// ---------------- persistent recurrence kernel (store-slot dataflow) ----------------
// Critical path per step: z0s -> dp -> dps -> S2 -> parts -> S3(4-wave) -> atts -> S4 -> z0s.
// gates1 and acc0/pregate run off the critical path.
// slot layout (ints) in bar:
//   z0s[256] @0, z1s[256] @256, dps[32] @512, atts[16] @544, parts[16][32] @576
__global__ __launch_bounds__(256, 2) void k_persist(
  const u16* __restrict__ peb, const u16* __restrict__ hsb,
  const u16* __restrict__ wc0p, const u16* __restrict__ wc1p, const u16* __restrict__ wdecb,
  const u16* __restrict__ wih0p, const u16* __restrict__ aey,
  const float* __restrict__ b_ih0, const float* __restrict__ b_hh0,
  const float* __restrict__ b_ih1, const float* __restrict__ b_hh1,
  const float* __restrict__ gvec, const int* __restrict__ hlens,
  u16* a1b0, u16* a1b1, float* dpbuf, float* part, float* partS, u16* xatt,
  u16* zall, int* bar)
{
  __shared__ __align__(16) u16 s_pe[TCH*512];
  __shared__ __align__(16) u16 s_hs[TCH*512];
  __shared__ __align__(16) float s_dp[512];
  __shared__ __align__(16) float s_gv[512];
  __shared__ __align__(16) float s_red[2048];
  __shared__ float s_c[64];
  __shared__ float s_bias[16];
  __shared__ float s_bias0[16];
  __shared__ float s_sp[4];
  __shared__ __align__(8) u16 s_h[64];

  int tid = threadIdx.x, blk = blockIdx.x;
  int wv = tid >> 6, ln = tid & 63;
  int s2_b = blk >> 5, s2_ch = blk & 31;
  int t0 = s2_ch * TCH;
  int hl = hlens[s2_b];
  bool isLow = (blk < 256);
  int hw = blk - 256;
  bool isdp = (!isLow) && ((hw & 7) == 0);   // dp duty spread
  int wdp = hw >> 3;

  int* z0s  = bar;
  int* z1s  = bar + 256;
  int* dps  = bar + 512;
  int* atts = bar + 544;
  int* parts= bar + 576;

  // ---- init: stage LDS-persistent data ----
  {
    const bfrag8* src_pe = (const bfrag8*)(peb + ((size_t)(s2_b*Tlen + t0))*512);
    const bfrag8* src_hs = (const bfrag8*)(hsb + ((size_t)(s2_b*Tlen + t0))*512);
    for (int idx = tid; idx < TCH*512/8; idx += 256){
      ((bfrag8*)s_pe)[idx] = src_pe[idx];
      ((bfrag8*)s_hs)[idx] = src_hs[idx];
    }
    for (int a = tid; a < 512; a += 256) s_gv[a] = gvec[a];
    if (isLow && tid < 16){
      int r = (tid>>2)*1024 + 4*blk + (tid&3);
      s_bias[tid] = b_ih1[r] + b_hh1[r];
    }
    if (!isLow && tid < 16){
      int r = (tid>>2)*1024 + 4*hw + (tid&3);
      s_bias0[tid] = b_ih0[r] + b_hh0[r];
    }
    if (tid < 64) s_c[tid] = 0.f;
  }
  __syncthreads();

  for (int i = 0; i < OL; i++){
    int par = i & 1;
    const u16* a1r = par ? a1b1 : a1b0;
    u16* a1w = par ? a1b0 : a1b1;
    float* dpc   = dpbuf + (size_t)par*(16*512);
    float* partc = part  + (size_t)par*(16*32*512);
    float* pSc   = partS + (size_t)par*(16*32);
    u16*   xac   = xatt  + (size_t)par*(16*512);

    f32x4 acc0 = {0.f,0.f,0.f,0.f};

    if (!isLow){
      // ======== dp stage (critical): only dp-duty blocks ========
      if (isdp){
        if (i >= 1){
          // per-wave wait: wave wv consumes z0 cols [wv*256,+256) = slots hw in
          // [wv*64,+64) = u64 words [wv*32,+32). Start MFMA as soon as OUR
          // producers are done, independent of other waves.
          const u64* z64 = (const u64*)z0s;
          bool d = (ln >= 32);
          for(;;){
            if (!d){ u64 v = ald64(&z64[wv*32 + ln]);
              d = ((int)(u32)v >= i) && ((int)(u32)(v >> 32) >= i); }
            if (__all(d)) break;
            __builtin_amdgcn_s_sleep(1);
          }
        }
        const u16* btd = wdecb + (size_t)wdp*16*DUNITS;
        f32x4 ad = {0.f,0.f,0.f,0.f};
        ad = mfma_loop_a(a1r + wv*256, KA1, btd + wv*256, DUNITS, 256, ad);
        int q = ln >> 4;
        #pragma unroll
        for (int r = 0; r < 4; r++) s_red[wv*256 + (q*4+r)*16 + (ln & 15)] = ad[r];
        __syncthreads();
        {
          float val = s_red[tid] + s_red[256+tid] + s_red[512+tid] + s_red[768+tid];
          int b = tid >> 4, al = tid & 15;
          astf(&dpc[b*512 + wdp*16 + al], val);
        }
        signal_slot(&dps[wdp], i + 1);
      }
      // pregate tile for step i (pure cached loads, hides under dps wait)
      acc0 = mfma_loop(aey + ((size_t)i*Bsz)*DUNITS + wv*256, DUNITS,
                       wih0p + (size_t)hw*16*DUNITS + wv*256, DUNITS, 256, acc0);
    }

    // ======== S2: energies + attc partials (all 512 blocks) ========
    wait_slots((const u64*)dps, 16, i + 1);
    ((u64*)s_dp)[tid] = ald64(((const u64*)(dpc + s2_b*512)) + tid);
    __syncthreads();
    {
      float dpr[8], gvr[8];
      {
        float4 d1 = *(const float4*)&s_dp[ln*8];
        float4 d2 = *(const float4*)&s_dp[ln*8+4];
        float4 g1 = *(const float4*)&s_gv[ln*8];
        float4 g2 = *(const float4*)&s_gv[ln*8+4];
        dpr[0]=d1.x; dpr[1]=d1.y; dpr[2]=d1.z; dpr[3]=d1.w;
        dpr[4]=d2.x; dpr[5]=d2.y; dpr[6]=d2.z; dpr[7]=d2.w;
        gvr[0]=g1.x; gvr[1]=g1.y; gvr[2]=g1.z; gvr[3]=g1.w;
        gvr[4]=g2.x; gvr[5]=g2.y; gvr[6]=g2.z; gvr[7]=g2.w;
      }
      float attc[8];
      #pragma unroll
      for (int j = 0; j < 8; j++) attc[j] = 0.f;
      float sp = 0.f;
      for (int lt = wv; lt < TCH; lt += 4){
        int t = t0 + lt;
        bool valid = (t < hl);
        float e = 0.f;
        if (valid){
          bfrag8 pv = *(const bfrag8*)&s_pe[lt*512 + ln*8];
          #pragma unroll
          for (int j = 0; j < 8; j++){
            float x = bf2f(((u16*)&pv)[j]) + dpr[j];
            e += gvr[j] * tanh_f(x);
          }
        }
        #pragma unroll
        for (int off = 32; off > 0; off >>= 1) e += __shfl_xor(e, off, 64);
        float p = valid ? __expf(2.0f * e) : 0.f;
        if (ln == 0) sp += p;
        bfrag8 hv = *(const bfrag8*)&s_hs[lt*512 + ln*8];
        #pragma unroll
        for (int j = 0; j < 8; j++) attc[j] += p * bf2f(((u16*)&hv)[j]);
      }
      *(float4*)&s_red[wv*512 + ln*8]     = make_float4(attc[0],attc[1],attc[2],attc[3]);
      *(float4*)&s_red[wv*512 + ln*8 + 4] = make_float4(attc[4],attc[5],attc[6],attc[7]);
      if (ln == 0) s_sp[wv] = sp;
      __syncthreads();
      {
        int e0 = 2*tid;
        float v0 = s_red[e0]   + s_red[512+e0]   + s_red[1024+e0]   + s_red[1536+e0];
        float v1 = s_red[e0+1] + s_red[512+e0+1] + s_red[1024+e0+1] + s_red[1536+e0+1];
        union { float f[2]; u64 q; } pu; pu.f[0]=v0; pu.f[1]=v1;
        ast64(&partc[((size_t)(s2_b*32 + s2_ch))*512 + e0], pu.q);
      }
      if (tid == 0) astf(&pSc[s2_b*32 + s2_ch], s_sp[0]+s_sp[1]+s_sp[2]+s_sp[3]);
      signal_slot(&parts[s2_b*32 + s2_ch], i + 1);
    }

    if (isLow){
      // ======== S3: attc reduce + normalize (blocks 0..15, ALL 4 waves) ========
      if (blk < 16){
        if (wv == 0){
          const int* myparts = parts + blk*32;
          bool dn = (ln >= 32);
          for(;;){
            if (!dn) dn = (ald32(&myparts[ln]) >= i + 1);
            if (__all(dn)) break;
            __builtin_amdgcn_s_sleep(1);
          }
        }
        __syncthreads();
        // 256-thread reduce: thread owns elements (2*tid, 2*tid+1), c2 ascending
        float v0 = 0.f, v1 = 0.f;
        const u64* pp = (const u64*)(partc + ((size_t)blk*32)*512) + tid;
        #pragma unroll 8
        for (int c2 = 0; c2 < 32; c2++){
          union { u64 q; float f[2]; } x; x.q = ald64(pp + (size_t)c2*256);
          v0 += x.f[0]; v1 += x.f[1];
        }
        if (wv == 0){
          float sp = (ln < 32) ? aldf(&pSc[blk*32 + ln]) : 0.f;
          #pragma unroll
          for (int off = 32; off > 0; off >>= 1) sp += __shfl_xor(sp, off, 64);
          if (ln == 0) s_sp[0] = 1.0f / sp;
        }
        __syncthreads();
        float rinv = s_sp[0];
        u32 wpk = (u32)f2bf(v0*rinv) | ((u32)f2bf(v1*rinv) << 16);
        ast32(((u32*)xac) + blk*256 + tid, wpk);
        signal_slot(&atts[blk], i + 1);
      }
      // ======== gates1 + cell1 (off critical path; overlaps S4/dp) ========
      if (i >= 1){
        if (i >= 2 && wv >= 2){
          // waves 2,3 consume z1 cols [(wv-2)*512,+512) = slots [(wv-2)*128,+128)
          // = u64 words [(wv-2)*64,+64). Waves 0,1 consume z0 (transitively
          // guaranteed via the dps wait) -> no wait.
          const u64* z64 = (const u64*)z1s;
          bool d = false;
          for(;;){
            if (!d){ u64 v = ald64(&z64[(wv-2)*64 + ln]);
              d = ((int)(u32)v >= i) && ((int)(u32)(v >> 32) >= i); }
            if (__all(d)) break;
            __builtin_amdgcn_s_sleep(1);
          }
        }
        const u16* bt = wc1p + (size_t)blk*16*KA1;
        f32x4 acc = {0.f,0.f,0.f,0.f};
        acc = mfma_loop_a(a1r + wv*512, KA1, bt + wv*512, KA1, 512, acc);
        int q = ln >> 4;
        #pragma unroll
        for (int r = 0; r < 4; r++) s_red[wv*256 + (q*4+r)*16 + (ln & 15)] = acc[r];
        __syncthreads();
        {
          float val = s_red[tid] + s_red[256+tid] + s_red[512+tid] + s_red[768+tid]
                    + s_bias[tid & 15];
          s_red[1024 + tid] = val;
        }
        __syncthreads();
        if (tid < 64){
          int b = tid >> 2, jj = tid & 3;
          float gi = s_red[1024 + b*16 + jj];
          float gf = s_red[1024 + b*16 + 4 + jj];
          float gg = s_red[1024 + b*16 + 8 + jj];
          float go = s_red[1024 + b*16 + 12 + jj];
          float c = s_c[tid];
          float cn = sigm(gf)*c + sigm(gi)*tanh_f(gg);
          float h  = sigm(go)*tanh_f(cn);
          s_c[tid] = cn;
          s_h[tid] = f2bf(h);
        }
        // fast wave0-local signal: 16 u64 stores by wave0, wave-level drain
        if (wv == 0){
          if (ln < 16){
            u64 hq = ((u64*)s_h)[ln];
            ast64(&a1w[ln*KA1 + 1024 + 4*blk], hq);
            *(u64*)&zall[((size_t)(i-1)*Bsz + ln)*DUNITS + 4*blk] = hq;
          }
          asm volatile("s_waitcnt vmcnt(0)" ::: "memory");
          if (ln == 0) ast32((u32*)&z1s[blk], (u32)(i + 1));
        }
      }
    } else {
      // ======== acc0 z0-part (overlaps S3), then S4 ========
      const u16* bt0 = wc0p + (size_t)hw*16*KX;
      acc0 = mfma_loop_a(a1r + wv*256, KA1, bt0 + wv*256, KX, 256, acc0);
      wait_slots((const u64*)atts, 8, i + 1);
      acc0 = mfma_loop_a(xac + wv*128, 512, bt0 + 1024 + wv*128, KX, 128, acc0);
      int q = ln >> 4;
      #pragma unroll
      for (int r = 0; r < 4; r++) s_red[wv*256 + (q*4+r)*16 + (ln & 15)] = acc0[r];
      __syncthreads();
      {
        float val = s_red[tid] + s_red[256+tid] + s_red[512+tid] + s_red[768+tid]
                  + s_bias0[tid & 15];
        s_red[1024 + tid] = val;
      }
      __syncthreads();
      if (tid < 64){
        int b = tid >> 2, jj = tid & 3;
        float gi = s_red[1024 + b*16 + jj];
        float gf = s_red[1024 + b*16 + 4 + jj];
        float gg = s_red[1024 + b*16 + 8 + jj];
        float go = s_red[1024 + b*16 + 12 + jj];
        float c = s_c[tid];
        float cn = sigm(gf)*c + sigm(gi)*tanh_f(gg);
        float h  = sigm(go)*tanh_f(cn);
        s_c[tid] = cn;
        s_h[tid] = f2bf(h);
      }
      // fast wave0-local signal: 16 u64 stores by wave0, wave-level drain
      if (wv == 0){
        if (ln < 16) ast64(&a1w[ln*KA1 + 4*hw], ((u64*)s_h)[ln]);
        asm volatile("s_waitcnt vmcnt(0)" ::: "memory");
        if (ln == 0) ast32((u32*)&z0s[hw], (u32)(i + 1));
      }
    }
  }

  // ======== tail: gates1 + cell1 for step 96 ========
  if (isLow){
    wait_slots((const u64*)z0s, 128, OL);
    wait_slots((const u64*)z1s, 128, OL);
    const u16* a1r = (OL & 1) ? a1b1 : a1b0;
    const u16* bt = wc1p + (size_t)blk*16*KA1;
    f32x4 acc = {0.f,0.f,0.f,0.f};
    acc = mfma_loop_a(a1r + wv*512, KA1, bt + wv*512, KA1, 512, acc);
    int q = ln >> 4;
    #pragma unroll
    for (int r = 0; r < 4; r++) s_red[wv*256 + (q*4+r)*16 + (ln & 15)] = acc[r];
    __syncthreads();
    {
      float val = s_red[tid] + s_red[256+tid] + s_red[512+tid] + s_red[768+tid]
                + s_bias[tid & 15];
      s_red[1024 + tid] = val;
    }
    __syncthreads();
    if (tid < 64){
      int b = tid >> 2, jj = tid & 3;
      float gi = s_red[1024 + b*16 + jj];
      float gf = s_red[1024 + b*16 + 4 + jj];
      float gg = s_red[1024 + b*16 + 8 + jj];
      float go = s_red[1024 + b*16 + 12 + jj];
      float c = s_c[tid];
      float cn = sigm(gf)*c + sigm(gi)*tanh_f(gg);
      float h  = sigm(go)*tanh_f(cn);
      s_h[tid] = f2bf(h);
    }
    __syncthreads();
    if (tid < 16)
      *(u64*)&zall[((size_t)LMAX*Bsz + tid)*DUNITS + 4*blk] = ((u64*)s_h)[tid];
  }
}

extern "C" void kernel_launch(void* const* d_in, const int* in_sizes, int n_in,
                              void* d_out, int out_size, void* d_ws, size_t ws_size,
                              hipStream_t stream)
{
  const float* hs     = (const float*)d_in[0];
  const int*   hlens  = (const int*)d_in[1];
  const int*   ys_pad = (const int*)d_in[2];
  const float* embed  = (const float*)d_in[3];
  const float* W_ih0  = (const float*)d_in[4];
  const float* W_hh0  = (const float*)d_in[5];
  const float* b_ih0  = (const float*)d_in[6];
  const float* b_hh0  = (const float*)d_in[7];
  const float* W_ih1  = (const float*)d_in[8];
  const float* W_hh1  = (const float*)d_in[9];
  const float* b_ih1  = (const float*)d_in[10];
  const float* b_hh1  = (const float*)d_in[11];
  const float* W_enc  = (const float*)d_in[12];
  const float* b_enc  = (const float*)d_in[13];
  const float* W_dec  = (const float*)d_in[14];
  const float* gvec   = (const float*)d_in[15];
  const float* W_out  = (const float*)d_in[16];
  const float* b_out  = (const float*)d_in[17];
  (void)in_sizes; (void)n_in; (void)out_size; (void)ws_size;

  char* w = (char*)d_ws;
  size_t off = 0;
  auto alloc = [&](size_t bytes)->char*{
    char* ptr = w + off;
    off += (bytes + 255) & ~(size_t)255;
    return ptr;
  };
  // --- zeroed state block: slots + a1 double buffers ---
  int*   bar  = (int*)alloc(8192);
  u16*  a1b0  = (u16*)alloc(Bsz*KA1*2);
  u16*  a1b1  = (u16*)alloc(Bsz*KA1*2);
  size_t state_bytes = off;
  // --- scratch (written before read every step) ---
  float* dpbuf = (float*)alloc(2*(size_t)Bsz*ATT*4);
  float* part  = (float*)alloc(2*(size_t)Bsz*32*512*4);
  float* partS = (float*)alloc(2*(size_t)Bsz*32*4);
  u16*  xatt   = (u16*)alloc(2*(size_t)Bsz*512*2);
  u16*  hsb    = (u16*)alloc((size_t)Bsz*Tlen*EPROJS*2);
  u16*  peb    = (u16*)alloc((size_t)Bsz*Tlen*ATT*2);
  u16*  wencb  = (u16*)alloc((size_t)ATT*EPROJS*2);
  u16*  wdecb  = (u16*)alloc((size_t)ATT*DUNITS*2);
  u16*  wc0p   = (u16*)alloc((size_t)G4*KX*2);
  u16*  wc1p   = (u16*)alloc((size_t)G4*KA1*2);
  u16*  wih0p  = (u16*)alloc((size_t)G4*DUNITS*2);
  u16*  woutb  = (u16*)alloc((size_t)ODIM*DUNITS*2);
  u16*  aey    = (u16*)alloc((size_t)NTOK*DUNITS*2);
  u16*  zall   = (u16*)alloc((size_t)NTOK*DUNITS*2);
  float* logits= (float*)alloc((size_t)NTOK*ODIM*4);
  float* nll   = (float*)alloc(NTOK*4);

  {
    int n = (int)(state_bytes / 4);
    k_zero<<<(n + 255)/256, 256, 0, stream>>>((float*)w, n);
  }

  k_cvt<<<2048,256,0,stream>>>(hs, hsb, Bsz*Tlen*EPROJS);
  k_cvt<<<256,256,0,stream>>>(W_enc, wencb, ATT*EPROJS);
  k_cvt<<<512,256,0,stream>>>(W_dec, wdecb, ATT*DUNITS);
  k_cvt<<<2048,256,0,stream>>>(W_out, woutb, ODIM*DUNITS);
  k_build_wc0p<<<4096,256,0,stream>>>(W_hh0, W_ih0, wc0p);
  k_build_wc1p<<<4096,256,0,stream>>>(W_ih1, W_hh1, wc1p);
  k_build_wih0p<<<4096,256,0,stream>>>(W_ih0, wih0p);
  k_build_aey<<<1024,256,0,stream>>>(embed, ys_pad, aey);

  k_gemm_preenc<<<(Bsz*Tlen/16)*(ATT/16), 64, 0, stream>>>(hsb, wencb, b_enc, peb);

  // persistent cooperative recurrence
  {
    void* args[] = {
      (void*)&peb, (void*)&hsb, (void*)&wc0p, (void*)&wc1p, (void*)&wdecb,
      (void*)&wih0p, (void*)&aey, (void*)&b_ih0, (void*)&b_hh0,
      (void*)&b_ih1, (void*)&b_hh1, (void*)&gvec, (void*)&hlens,
      (void*)&a1b0, (void*)&a1b1, (void*)&dpbuf, (void*)&part, (void*)&partS,
      (void*)&xatt, (void*)&zall, (void*)&bar
    };
    hipLaunchCooperativeKernel((const void*)k_persist, dim3(NWG), dim3(256),
                               args, 0, stream);
  }

  k_gemm_logits<<<OL*313, 64, 0, stream>>>(zall, woutb, b_out, logits);
  k_nll<<<NTOK,256,0,stream>>>(logits, ys_pad, nll);
  k_loss<<<1,256,0,stream>>>(nll, (float*)d_out);
}